// Round 12
// baseline (20.848 us; speedup 1.0000x reference)
//
#include <hip/hip_runtime.h>
#include <math.h>

// Persistent-ish decomposition: each WAVE processes TWO consecutive 64-anchor
// chunk-instances (2w, 2w+1) of the flattened (batch, chunk) space. 6,120
// waves (1,530 blocks x 4 waves) -> all waves resident in ONE scheduling round
// (6 waves/SIMD), eliminating the ~12 rounds of wave churn of the 1-chunk/wave
// version. Chunk pairs never cross a batch (3060 even) nor a level boundary
// (level chunk counts 2304/576/144/36 all even), so batch+level decode and the
// box load/transform happen once per wave. Per-chunk body (prune ballot ->
// LDS compact -> division-free argmax -> epilogue) is the verified r7/r10 code;
// IoU + threshold math bit-identical to the verified r2 kernel.

__global__ __launch_bounds__(256) void anchors_kernel(
    const int*   __restrict__ labels,   // [B, N]
    const float* __restrict__ boxes,    // [B, N, 4] x1,y1,x2,y2
    float*       __restrict__ out,      // [B*A] cls(float) then [B*A*4] loc
    int B, int N, int A, int S)
{
    __shared__ float4 s_corn[256];   // per-wave segments of 64
    __shared__ float  s_area[256];
    __shared__ float4 s_xywh[256];
    __shared__ int    s_lab[256];

    const int t    = threadIdx.x;
    const int lane = t & 63;
    const int wid  = t >> 6;
    const int base = wid * 64;

    const int chunksPerB = A >> 6;                  // 3060
    const int wgid  = blockIdx.x * 4 + wid;         // wave global id [0, 6120)
    const int inst0 = 2 * wgid;                     // first chunk instance
    if (inst0 >= 2 * chunksPerB * B / 2 * 2) {}     // (grid exact; no tail)

    const int b  = inst0 / chunksPerB;              // same b for both chunks
    const int c0 = inst0 - b * chunksPerB;          // even; c1 = c0+1 same level

    // ---- wave-uniform level decode (once; pair never crosses a level) ----
    int r0 = c0 << 6;                               // anchor offset in batch
    int lvl = 0, fm = S >> 2;                       // 128,64,32,16 (S=512 exact)
    #pragma unroll
    for (int i = 0; i < 3; ++i) {
        int cnt = fm * fm * 9;
        if (r0 >= cnt) { r0 -= cnt; lvl = i + 1; fm >>= 1; }
    }
    const int   lfm  = 31 - __clz(fm);
    const float grid = (float)(4 << lvl);                            // 4,8,16,32
    const float sl   = (float)((lvl == 3) ? 128 : (4 << (2 * lvl))); // 4,16,64,128
    const float ext  = 1.41422f * sl + 2.0f;        // conservative prune slack

    // ---- once per wave: load box[lane] + labels, transform to regs ----
    float4 bxr = make_float4(0.f, 0.f, 0.f, 0.f);
    float bcx = 0, bcy = 0, bw = 0, bh = 0;
    float kx1 = 0, ky1 = 0, kx2 = 0, ky2 = 0, karea = 0;
    int   blab = 0;
    if (lane < N) {
        bxr = reinterpret_cast<const float4*>(boxes)[b * N + lane];
        bcx = (bxr.x + bxr.z) * 0.5f;
        bcy = (bxr.y + bxr.w) * 0.5f;
        bw  = bxr.z - bxr.x + 1.0f;
        bh  = bxr.w - bxr.y + 1.0f;
        kx1 = bcx - bw * 0.5f;  ky1 = bcy - bh * 0.5f;
        kx2 = bcx + bw * 0.5f;  ky2 = bcy + bh * 0.5f;
        karea = (kx2 - kx1 + 1.0f) * (ky2 - ky1 + 1.0f);
        blab  = labels[b * N + lane];
    }

    // ---- two consecutive chunks, same level, same batch ----
    #pragma unroll
    for (int it = 0; it < 2; ++it) {
        const int r0i = r0 + (it << 6);             // in-level anchor offset

        // chunk anchor bbox
        const int cell_lo = r0i / 9;
        const int cell_hi = (r0i + 63) / 9;
        const int ci_lo = cell_lo >> lfm, ci_hi = cell_hi >> lfm;
        int cj_lo, cj_hi;
        if (ci_lo == ci_hi) { cj_lo = cell_lo & (fm - 1); cj_hi = cell_hi & (fm - 1); }
        else                { cj_lo = 0;                  cj_hi = fm - 1; }
        const float bbx1 = ((float)cj_lo + 0.5f) * grid - ext;
        const float bbx2 = ((float)cj_hi + 0.5f) * grid + ext;
        const float bby1 = ((float)ci_lo + 0.5f) * grid - ext;
        const float bby2 = ((float)ci_hi + 0.5f) * grid + ext;

        // prune on raw coords (false-keeps harmless: zero-IoU can't win)
        bool pred = (lane < N) &&
                    (fminf(bbx2, bxr.z) - fmaxf(bbx1, bxr.x) + 1.0f > 0.0f) &&
                    (fminf(bby2, bxr.w) - fmaxf(bby1, bxr.y) + 1.0f > 0.0f);
        pred = pred || (lane == 0);                 // force-keep box 0
        unsigned long long mask = __ballot(pred);
        if (pred) {
            int pos = base + __popcll(mask & ((1ull << lane) - 1ull));
            s_corn[pos] = make_float4(kx1, ky1, kx2, ky2);
            s_area[pos] = karea;
            s_xywh[pos] = make_float4(bcx, bcy, bw, bh);
            s_lab[pos]  = blab;
        }
        const int L = __popcll(mask);

        // per-thread anchor
        const int r    = r0i + lane;
        const int cell = r / 9;
        const int k    = r - cell * 9;
        const int cj   = cell & (fm - 1);
        const int ci   = cell >> lfm;

        // anchor w/h: compile-time constants, bit-equal to numpy double math
        const float cwk =
            (k < 3) ? ((k == 0) ? 0.70710678118654752f
                     : (k == 1) ? 1.41421356237309515f
                                : 0.53033008588991064f)
          : (k < 6) ? ((k == 3) ? 1.0f : (k == 4) ? 2.0f : 0.75f)
                    : ((k == 6) ? 1.41421356237309515f
                     : (k == 7) ? 2.82842712474619029f
                                : 1.06066017177982129f);
        const float chk =
            (k < 3) ? ((k == 0) ? 1.41421356237309515f
                     : (k == 1) ? 2.82842712474619029f
                                : 1.06066017177982129f)
          : (k < 6) ? ((k == 3) ? 1.0f : (k == 4) ? 2.0f : 0.75f)
                    : ((k == 6) ? 0.70710678118654752f
                     : (k == 7) ? 1.41421356237309515f
                                : 0.53033008588991064f);
        const float aw = cwk * sl;
        const float ah = chk * sl;

        const float acx = ((float)cj + 0.5f) * grid;
        const float acy = ((float)ci + 0.5f) * grid;
        const float ax1 = acx - aw * 0.5f;
        const float ay1 = acy - ah * 0.5f;
        const float ax2 = acx + aw * 0.5f;
        const float ay2 = acy + ah * 0.5f;
        const float area_a = (ax2 - ax1 + 1.0f) * (ay2 - ay1 + 1.0f);

        // argmax IoU over compacted list, division-free compare
        float best_in = 0.0f, best_un = 1.0f;
        int   bj = 0;                               // zero row -> box 0
        for (int j = 0; j < L; ++j) {
            float4 c = s_corn[base + j];
            float iw = fmaxf(fminf(ax2, c.z) - fmaxf(ax1, c.x) + 1.0f, 0.0f);
            float ih = fmaxf(fminf(ay2, c.w) - fmaxf(ay1, c.y) + 1.0f, 0.0f);
            float in_ = iw * ih;
            float un_ = (area_a + s_area[base + j]) - in_;
            bool better = (in_ * best_un) > (best_in * un_);
            best_in = better ? in_ : best_in;
            best_un = better ? un_ : best_un;
            bj      = better ? j   : bj;
        }
        const float best = best_in / best_un;       // exact IEEE; ref operands

        float4 m   = s_xywh[base + bj];
        int    lab = s_lab[base + bj];

        int cls = lab;
        if (best < 0.5f) cls = 0;
        if (best > 0.4f && best < 0.5f) cls = -1;

        // v_rcp_f32 (~1 ulp) loc divides; tolerance 7.8e-3, err <= ~3e-5
        const float rcp_aw = __builtin_amdgcn_rcpf(aw);
        const float rcp_ah = __builtin_amdgcn_rcpf(ah);
        float4 loc;
        loc.x = (m.x - acx) * rcp_aw;
        loc.y = (m.y - acy) * rcp_ah;
        loc.z = __logf(m.z * rcp_aw);
        loc.w = __logf(m.w * rcp_ah);

        const size_t gid = (size_t)b * A + (size_t)(((c0 + it) << 6) + lane);
        out[gid] = (float)cls;
        reinterpret_cast<float4*>(out + (size_t)B * A)[gid] = loc;
    }
}

extern "C" void kernel_launch(void* const* d_in, const int* in_sizes, int n_in,
                              void* d_out, int out_size, void* d_ws, size_t ws_size,
                              hipStream_t stream) {
    const int S = 512;  // setup_inputs() fixed input_size
    int A = 0;
    for (int i = 0; i < 4; ++i) {
        int f = (S + (1 << (i + 2)) - 1) >> (i + 2);
        A += f * f * 9;
    }
    const int B = out_size / (5 * A);       // out = B*A cls + B*A*4 loc
    const int N = in_sizes[0] / B;          // labels is [B, N]

    const int chunksPerB = A / 64;          // 3060
    const int totalInst  = chunksPerB * B;  // 12240 (even)
    const int waves      = totalInst / 2;   // 6120, 2 chunks per wave
    const int blocks     = waves / 4;       // 1530 blocks x 4 waves

    anchors_kernel<<<blocks, 256, 0, stream>>>(
        (const int*)d_in[0], (const float*)d_in[1], (float*)d_out, B, N, A, S);
}

// Round 13
// 17.455 us; speedup vs baseline: 1.1944x; 1.1944x over previous
//
#include <hip/hip_runtime.h>
#include <math.h>

// r7 decomposition (the measured optimum): one thread per (batch, anchor);
// one 64-anchor chunk per WAVE; 256-thread blocks (4 independent waves, zero
// barriers). Box+label loads issued FIRST so VMEM latency overlaps the
// wave-uniform decode. N64 specialization removes the lane<N guard.
// Per-wave prune (raw coords, conservative): pruned boxes have IoU exactly 0
// for every anchor in the wave -> argmax unchanged; box 0 force-kept so
// all-zero rows resolve to box 0 (= jnp.argmax of zeros) with best=0 exactly.
// IoU + threshold math bit-identical to the verified r2/r7 kernels.

template <bool N64>
__global__ __launch_bounds__(256) void anchors_kernel(
    const int*   __restrict__ labels,   // [B, N]
    const float* __restrict__ boxes,    // [B, N, 4] x1,y1,x2,y2
    float*       __restrict__ out,      // [B*A] cls(float) then [B*A*4] loc
    int B, int N, int A, int S)
{
    __shared__ float4 s_corn[256];   // per-wave segments of 64
    __shared__ float  s_area[256];
    __shared__ float4 s_xywh[256];
    __shared__ int    s_lab[256];

    const int t    = threadIdx.x;
    const int lane = t & 63;
    const int wid  = t >> 6;
    const int b    = blockIdx.y;

    // ---- issue global loads immediately (latency overlaps decode below) ----
    float4 bxr  = make_float4(0.f, 0.f, 0.f, 0.f);
    int    blab = 0;
    if (N64 || lane < N) {
        bxr  = reinterpret_cast<const float4*>(boxes)[b * N + lane];
        blab = labels[b * N + lane];
    }

    const int wr0 = blockIdx.x * 256 + wid * 64;    // wave's first anchor
    if (wr0 >= A) return;

    // ---- wave-uniform level decode (level sizes are multiples of 64) ----
    int r0 = wr0;
    int lvl = 0, fm = S >> 2;                       // 128,64,32,16 (S=512 exact)
    #pragma unroll
    for (int i = 0; i < 3; ++i) {
        int cnt = fm * fm * 9;
        if (r0 >= cnt) { r0 -= cnt; lvl = i + 1; fm >>= 1; }
    }
    const int   lfm  = 31 - __clz(fm);
    const float grid = (float)(4 << lvl);                            // 4,8,16,32
    const float sl   = (float)((lvl == 3) ? 128 : (4 << (2 * lvl))); // 4,16,64,128

    // ---- wave anchor bbox over its 64 anchors ----
    const int cell_lo = r0 / 9;
    const int cell_hi = (r0 + 63) / 9;
    const int ci_lo = cell_lo >> lfm, ci_hi = cell_hi >> lfm;
    int cj_lo, cj_hi;
    if (ci_lo == ci_hi) { cj_lo = cell_lo & (fm - 1); cj_hi = cell_hi & (fm - 1); }
    else                { cj_lo = 0;                  cj_hi = fm - 1; }
    const float ext  = 1.41422f * sl + 2.0f;   // conservative slack (false keeps ok)
    const float bbx1 = ((float)cj_lo + 0.5f) * grid - ext;
    const float bbx2 = ((float)cj_hi + 0.5f) * grid + ext;
    const float bby1 = ((float)ci_lo + 0.5f) * grid - ext;
    const float bby2 = ((float)ci_hi + 0.5f) * grid + ext;

    // ---- prune on raw coords, transform kept boxes, compact into LDS ----
    int L;
    {
        bool pred = (N64 || lane < N) &&
                    (fminf(bbx2, bxr.z) - fmaxf(bbx1, bxr.x) + 1.0f > 0.0f) &&
                    (fminf(bby2, bxr.w) - fmaxf(bby1, bxr.y) + 1.0f > 0.0f);
        pred = pred || (lane == 0);              // force-keep box 0
        unsigned long long mask = __ballot(pred);
        if (pred) {
            float cx = (bxr.x + bxr.z) * 0.5f;
            float cy = (bxr.y + bxr.w) * 0.5f;
            float w  = bxr.z - bxr.x + 1.0f;
            float h  = bxr.w - bxr.y + 1.0f;
            float x1 = cx - w * 0.5f, y1 = cy - h * 0.5f;
            float x2 = cx + w * 0.5f, y2 = cy + h * 0.5f;
            int pos = wid * 64 + __popcll(mask & ((1ull << lane) - 1ull));
            s_corn[pos] = make_float4(x1, y1, x2, y2);
            s_area[pos] = (x2 - x1 + 1.0f) * (y2 - y1 + 1.0f);
            s_xywh[pos] = make_float4(cx, cy, w, h);
            s_lab[pos]  = blab;
        }
        L = __popcll(mask);
    }

    // ---- per-thread anchor ----
    const int r    = r0 + lane;
    const int cell = r / 9;                 // magic-mul (compile-time 9)
    const int k    = r - cell * 9;
    const int cj   = cell & (fm - 1);
    const int ci   = cell >> lfm;

    // anchor w/h: compile-time float constants, bit-equal to numpy's
    // float32(sqrt(area/ar)*sr) (pow2 scalings commute with rounding).
    const float cwk =
        (k < 3) ? ((k == 0) ? 0.70710678118654752f
                 : (k == 1) ? 1.41421356237309515f
                            : 0.53033008588991064f)
      : (k < 6) ? ((k == 3) ? 1.0f : (k == 4) ? 2.0f : 0.75f)
                : ((k == 6) ? 1.41421356237309515f
                 : (k == 7) ? 2.82842712474619029f
                            : 1.06066017177982129f);
    const float chk =
        (k < 3) ? ((k == 0) ? 1.41421356237309515f
                 : (k == 1) ? 2.82842712474619029f
                            : 1.06066017177982129f)
      : (k < 6) ? ((k == 3) ? 1.0f : (k == 4) ? 2.0f : 0.75f)
                : ((k == 6) ? 0.70710678118654752f
                 : (k == 7) ? 1.41421356237309515f
                            : 0.53033008588991064f);
    const float aw = cwk * sl;
    const float ah = chk * sl;

    const float acx = ((float)cj + 0.5f) * grid;
    const float acy = ((float)ci + 0.5f) * grid;
    const float ax1 = acx - aw * 0.5f;
    const float ay1 = acy - ah * 0.5f;
    const float ax2 = acx + aw * 0.5f;
    const float ay2 = acy + ah * 0.5f;
    const float area_a = (ax2 - ax1 + 1.0f) * (ay2 - ay1 + 1.0f);

    // ---- argmax IoU over compacted list, division-free compare ----
    float best_in = 0.0f, best_un = 1.0f;
    int   bj = 0;                           // zero row -> box 0
    const int base = wid * 64;
    for (int j = 0; j < L; ++j) {
        float4 c = s_corn[base + j];
        float iw = fmaxf(fminf(ax2, c.z) - fmaxf(ax1, c.x) + 1.0f, 0.0f);
        float ih = fmaxf(fminf(ay2, c.w) - fmaxf(ay1, c.y) + 1.0f, 0.0f);
        float in_ = iw * ih;
        float un_ = (area_a + s_area[base + j]) - in_;
        bool better = (in_ * best_un) > (best_in * un_);
        best_in = better ? in_ : best_in;
        best_un = better ? un_ : best_un;
        bj      = better ? j   : bj;
    }
    const float best = best_in / best_un;   // exact IEEE; operands match reference

    float4 m   = s_xywh[base + bj];
    int    lab = s_lab[base + bj];

    int cls = lab;
    if (best < 0.5f) cls = 0;
    if (best > 0.4f && best < 0.5f) cls = -1;

    // v_rcp_f32 (~1 ulp) loc divides; tolerance 7.8e-3, err <= ~3e-5
    const float rcp_aw = __builtin_amdgcn_rcpf(aw);
    const float rcp_ah = __builtin_amdgcn_rcpf(ah);
    float4 loc;
    loc.x = (m.x - acx) * rcp_aw;
    loc.y = (m.y - acy) * rcp_ah;
    loc.z = __logf(m.z * rcp_aw);
    loc.w = __logf(m.w * rcp_ah);

    const size_t gid = (size_t)b * A + (size_t)(wr0 + lane);
    out[gid] = (float)cls;
    reinterpret_cast<float4*>(out + (size_t)B * A)[gid] = loc;
}

extern "C" void kernel_launch(void* const* d_in, const int* in_sizes, int n_in,
                              void* d_out, int out_size, void* d_ws, size_t ws_size,
                              hipStream_t stream) {
    const int S = 512;  // setup_inputs() fixed input_size
    int A = 0;
    for (int i = 0; i < 4; ++i) {
        int f = (S + (1 << (i + 2)) - 1) >> (i + 2);
        A += f * f * 9;
    }
    const int B = out_size / (5 * A);       // out = B*A cls + B*A*4 loc
    const int N = in_sizes[0] / B;          // labels is [B, N]

    dim3 gridDim((A + 255) / 256, B);       // 4 waves/block, 64 anchors/wave

    if (N == 64) {
        anchors_kernel<true><<<gridDim, 256, 0, stream>>>(
            (const int*)d_in[0], (const float*)d_in[1], (float*)d_out, B, N, A, S);
    } else {
        anchors_kernel<false><<<gridDim, 256, 0, stream>>>(
            (const int*)d_in[0], (const float*)d_in[1], (float*)d_out, B, N, A, S);
    }
}